// Round 1
// baseline (666.443 us; speedup 1.0000x reference)
//
#include <hip/hip_runtime.h>

#define N_NODES 100000
#define N_EDGES 1600000
#define NG 64
#define NC 8
#define HD 128

typedef __attribute__((ext_vector_type(8))) __bf16 bf16x8;
typedef __attribute__((ext_vector_type(4))) float f32x4;

// ---------------- CSR build ----------------

__global__ void hist_k(const int* __restrict__ dst, int* __restrict__ deg) {
  int e = blockIdx.x * 256 + threadIdx.x;
  if (e < N_EDGES) atomicAdd(&deg[dst[e]], 1);
}

__launch_bounds__(1024)
__global__ void scan_k(const int* __restrict__ deg, int* __restrict__ row_ptr,
                       int* __restrict__ cursor) {
  __shared__ int wsum[16];
  int t = threadIdx.x, lane = t & 63, wid = t >> 6;
  int carry = 0;
  for (int base = 0; base < N_NODES; base += 1024) {
    int i = base + t;
    int v = (i < N_NODES) ? deg[i] : 0;
    int s = v;
#pragma unroll
    for (int off = 1; off < 64; off <<= 1) {
      int u = __shfl_up(s, off);
      if (lane >= off) s += u;
    }
    if (lane == 63) wsum[wid] = s;
    __syncthreads();
    if (wid == 0) {
      int ws = (lane < 16) ? wsum[lane] : 0;
#pragma unroll
      for (int off = 1; off < 16; off <<= 1) {
        int u = __shfl_up(ws, off);
        if (lane >= off) ws += u;
      }
      if (lane < 16) wsum[lane] = ws;
    }
    __syncthreads();
    int excl = carry + ((wid > 0) ? wsum[wid - 1] : 0) + (s - v);
    if (i < N_NODES) { row_ptr[i] = excl; cursor[i] = excl; }
    carry += wsum[15];
    __syncthreads();
  }
  if (t == 0) row_ptr[N_NODES] = carry;
}

__global__ void fill_k(const int* __restrict__ src, const int* __restrict__ dst,
                       int* __restrict__ cursor, int* __restrict__ csr) {
  int e = blockIdx.x * 256 + threadIdx.x;
  if (e < N_EDGES) {
    int p = atomicAdd(&cursor[dst[e]], 1);
    csr[p] = src[e];
  }
}

// ---------------- conv1: x1 = relu(agg3 @ Wrel1^T + brel1 + xs @ Wroot1^T) ----------------
// One wave per node. All lanes redundantly accumulate the 3-dim edge sum
// (broadcast loads), then each lane computes 2 of the 128 output features.
// x1 written as bf16 into xcat[n][128..255].

__global__ void conv1_k(const float* __restrict__ x, const int* __restrict__ row_ptr,
                        const int* __restrict__ csr, const float* __restrict__ Wroot1,
                        const float* __restrict__ Wrel1, const float* __restrict__ brel1,
                        __bf16* __restrict__ xcat) {
  int node = blockIdx.x * 4 + (threadIdx.x >> 6);
  if (node >= N_NODES) return;
  int lane = threadIdx.x & 63;
  int beg = row_ptr[node], end = row_ptr[node + 1];
  int deg = end - beg;
  int idx = (lane < deg) ? csr[beg + lane] : 0;  // preload indices lane-parallel
  float a0 = 0.f, a1 = 0.f, a2 = 0.f;
  int dmain = deg < 64 ? deg : 64;
  for (int j = 0; j < dmain; j++) {
    int s = __shfl(idx, j);
    const float* xp = x + (size_t)s * 5;
    a0 += xp[2]; a1 += xp[3]; a2 += xp[4];
  }
  for (int e = beg + 64; e < end; e++) {  // rare tail (deg > 64)
    int s = csr[e];
    const float* xp = x + (size_t)s * 5;
    a0 += xp[2]; a1 += xp[3]; a2 += xp[4];
  }
  const float* xn = x + (size_t)node * 5;
  float r0 = xn[2], r1 = xn[3], r2 = xn[4];
  __bf16* orow = xcat + (size_t)node * 256 + 128;
#pragma unroll
  for (int hh = 0; hh < 2; hh++) {
    int h = lane + hh * 64;
    float v = brel1[h]
            + a0 * Wrel1[h * 3 + 0] + a1 * Wrel1[h * 3 + 1] + a2 * Wrel1[h * 3 + 2]
            + r0 * Wroot1[h * 3 + 0] + r1 * Wroot1[h * 3 + 1] + r2 * Wroot1[h * 3 + 2];
    orow[h] = (__bf16)fmaxf(v, 0.f);
  }
}

// ---------------- agg2: xcat[n][0..127] = sum over in-edges of x1[src] ----------------
// One wave per node; each lane owns 2 features (one dword of the bf16 row).

__global__ void agg2_k(const int* __restrict__ row_ptr, const int* __restrict__ csr,
                       __bf16* xcat) {
  int node = blockIdx.x * 4 + (threadIdx.x >> 6);
  if (node >= N_NODES) return;
  int lane = threadIdx.x & 63;
  int beg = row_ptr[node], end = row_ptr[node + 1];
  int deg = end - beg;
  int idx = (lane < deg) ? csr[beg + lane] : 0;
  float s0 = 0.f, s1 = 0.f;
  int dmain = deg < 64 ? deg : 64;
  for (int j = 0; j < dmain; j++) {
    int srcn = __shfl(idx, j);
    unsigned int u = ((const unsigned int*)(xcat + (size_t)srcn * 256 + 128))[lane];
    s0 += __uint_as_float(u << 16);
    s1 += __uint_as_float(u & 0xffff0000u);
  }
  for (int e = beg + 64; e < end; e++) {
    int srcn = csr[e];
    unsigned int u = ((const unsigned int*)(xcat + (size_t)srcn * 256 + 128))[lane];
    s0 += __uint_as_float(u << 16);
    s1 += __uint_as_float(u & 0xffff0000u);
  }
  unsigned int lo = __float_as_uint((float)(__bf16)s0) >> 16;
  unsigned int hi = __float_as_uint((float)(__bf16)s1) & 0xffff0000u;
  ((unsigned int*)(xcat + (size_t)node * 256))[lane] = lo | hi;
}

// ---------------- weight concat for conv2 GEMM ----------------
// Wc[h][k] = Wrel2[h][k] (k<128) | Wroot2[h][k-128], bf16.

__global__ void build_wc_k(const float* __restrict__ Wrel2, const float* __restrict__ Wroot2,
                           __bf16* __restrict__ Wc) {
  int i = blockIdx.x * 256 + threadIdx.x;  // 128*256 = 32768
  int h = i >> 8, k = i & 255;
  float v = (k < 128) ? Wrel2[h * 128 + k] : Wroot2[h * 128 + (k - 128)];
  Wc[i] = (__bf16)v;
}

// ---------------- conv2 GEMM: x2 = relu(xcat @ Wc^T + brel2), MFMA bf16 ----------------
// Wave computes a 16-node x 128-h tile, K=256. A/B frags are k-contiguous 16B loads.

__launch_bounds__(256)
__global__ void gemm2_k(const __bf16* __restrict__ xcat, const __bf16* __restrict__ Wc,
                        const float* __restrict__ brel2, __bf16* __restrict__ x2) {
  int wid = threadIdx.x >> 6, lane = threadIdx.x & 63;
  int nb = (blockIdx.x * 4 + wid) * 16;
  if (nb >= N_NODES) return;
  int r = lane & 15, ko = lane >> 4;
  const __bf16* arow = xcat + (size_t)(nb + r) * 256 + ko * 8;
  const __bf16* brow = Wc + (size_t)r * 256 + ko * 8;
  f32x4 acc[8];
#pragma unroll
  for (int i = 0; i < 8; i++) acc[i] = (f32x4){0.f, 0.f, 0.f, 0.f};
#pragma unroll
  for (int kb = 0; kb < 256; kb += 32) {
    bf16x8 a = *(const bf16x8*)(arow + kb);
#pragma unroll
    for (int ht = 0; ht < 8; ht++) {
      bf16x8 b = *(const bf16x8*)(brow + (size_t)ht * 16 * 256 + kb);
      acc[ht] = __builtin_amdgcn_mfma_f32_16x16x32_bf16(a, b, acc[ht], 0, 0, 0);
    }
  }
  // C/D layout: col = lane&15 (h within tile), row = (lane>>4)*4 + rr (node within tile)
#pragma unroll
  for (int ht = 0; ht < 8; ht++) {
    int h = ht * 16 + r;
    float bias = brel2[h];
#pragma unroll
    for (int rr = 0; rr < 4; rr++) {
      int node = nb + ko * 4 + rr;
      float v = acc[ht][rr] + bias;
      x2[(size_t)node * 128 + h] = (__bf16)fmaxf(v, 0.f);
    }
  }
}

// ---------------- segment_max over h = [x1 | x2] into g (G x 256) ----------------
// batch is sorted: block scans 128 contiguous nodes with running max,
// flushes one atomicMax per segment change. Values >= 0 so uint compare works.

__global__ void segmax_k(const __bf16* __restrict__ xcat, const __bf16* __restrict__ x2,
                         const int* __restrict__ batch, unsigned int* __restrict__ g) {
  int t = threadIdx.x;  // 256: t<128 -> x1 feature t, else x2 feature t-128
  int n0 = blockIdx.x * 128;
  if (n0 >= N_NODES) return;
  int n1 = n0 + 128 < N_NODES ? n0 + 128 : N_NODES;
  int cur = batch[n0];
  float m = 0.f;
  for (int n = n0; n < n1; n++) {
    int b = batch[n];
    if (b != cur) {
      atomicMax(&g[cur * 256 + t], __float_as_uint(m));
      cur = b; m = 0.f;
    }
    float v = (t < 128) ? (float)xcat[(size_t)n * 256 + 128 + t]
                        : (float)x2[(size_t)n * 128 + (t - 128)];
    m = fmaxf(m, v);
  }
  atomicMax(&g[cur * 256 + t], __float_as_uint(m));
}

// ---------------- MLP head + log_softmax (single block) ----------------

__global__ void head_k(const float* __restrict__ g, const float* __restrict__ exinfo,
                       const float* __restrict__ W1, const float* __restrict__ b1,
                       const float* __restrict__ W2, const float* __restrict__ b2,
                       const float* __restrict__ W3, const float* __restrict__ b3,
                       float* __restrict__ out) {
  __shared__ float g1[64][64];
  __shared__ float g2[64][32];
  __shared__ float lg[64][8];
  int t = threadIdx.x;
  for (int o = t; o < 64 * 64; o += 256) {
    int rr = o >> 6, c = o & 63;
    float s = b1[c];
    const float* w = W1 + c * 266;
    const float* gr = g + rr * 256;
    for (int k = 0; k < 256; k++) s += gr[k] * w[k];
    const float* er = exinfo + rr * 10;
    for (int k = 0; k < 10; k++) s += er[k] * w[256 + k];
    g1[rr][c] = fmaxf(s, 0.f);
  }
  __syncthreads();
  for (int o = t; o < 64 * 32; o += 256) {
    int rr = o >> 5, c = o & 31;
    float s = b2[c];
    for (int k = 0; k < 64; k++) s += g1[rr][k] * W2[c * 64 + k];
    g2[rr][c] = fmaxf(s, 0.f);
  }
  __syncthreads();
  for (int o = t; o < 64 * 8; o += 256) {
    int rr = o >> 3, c = o & 7;
    float s = b3[c];
    for (int k = 0; k < 32; k++) s += g2[rr][k] * W3[c * 32 + k];
    lg[rr][c] = s;
  }
  __syncthreads();
  if (t < 64) {
    float mx = lg[t][0];
    for (int c = 1; c < 8; c++) mx = fmaxf(mx, lg[t][c]);
    float se = 0.f;
    for (int c = 0; c < 8; c++) se += expf(lg[t][c] - mx);
    float lse = mx + logf(se);
    for (int c = 0; c < 8; c++) out[t * 8 + c] = lg[t][c] - lse;
  }
}

// ---------------- launch ----------------

extern "C" void kernel_launch(void* const* d_in, const int* in_sizes, int n_in,
                              void* d_out, int out_size, void* d_ws, size_t ws_size,
                              hipStream_t stream) {
  const float* x      = (const float*)d_in[0];
  const int*   edge   = (const int*)d_in[1];
  const int*   batch  = (const int*)d_in[2];
  const float* exinfo = (const float*)d_in[3];
  const float* Wroot1 = (const float*)d_in[4];
  const float* Wrel1  = (const float*)d_in[5];
  const float* brel1  = (const float*)d_in[6];
  const float* Wroot2 = (const float*)d_in[7];
  const float* Wrel2  = (const float*)d_in[8];
  const float* brel2  = (const float*)d_in[9];
  const float* W1     = (const float*)d_in[10];
  const float* b1     = (const float*)d_in[11];
  const float* W2     = (const float*)d_in[12];
  const float* b2     = (const float*)d_in[13];
  const float* W3     = (const float*)d_in[14];
  const float* b3     = (const float*)d_in[15];
  const int* src = edge;
  const int* dst = edge + N_EDGES;

  char* p = (char*)d_ws;
  auto alloc = [&](size_t bytes) {
    char* q = p;
    p += (bytes + 511) & ~(size_t)511;
    return (void*)q;
  };
  __bf16*       Wc      = (__bf16*)alloc(128 * 256 * 2);
  unsigned int* g       = (unsigned int*)alloc(64 * 256 * 4);
  int*          deg     = (int*)alloc((size_t)N_NODES * 4);
  int*          row_ptr = (int*)alloc((size_t)(N_NODES + 1) * 4);
  int*          cursor  = (int*)alloc((size_t)N_NODES * 4);
  int*          csr     = (int*)alloc((size_t)N_EDGES * 4);
  __bf16*       xcat    = (__bf16*)alloc((size_t)N_NODES * 256 * 2);
  __bf16*       x2      = (__bf16*)alloc((size_t)N_NODES * 128 * 2);

  hipMemsetAsync(deg, 0, (size_t)N_NODES * 4, stream);
  hipMemsetAsync(g, 0, 64 * 256 * 4, stream);
  build_wc_k<<<128, 256, 0, stream>>>(Wrel2, Wroot2, Wc);
  hist_k<<<6250, 256, 0, stream>>>(dst, deg);
  scan_k<<<1, 1024, 0, stream>>>(deg, row_ptr, cursor);
  fill_k<<<6250, 256, 0, stream>>>(src, dst, cursor, csr);
  conv1_k<<<25000, 256, 0, stream>>>(x, row_ptr, csr, Wroot1, Wrel1, brel1, xcat);
  agg2_k<<<25000, 256, 0, stream>>>(row_ptr, csr, xcat);
  gemm2_k<<<1563, 256, 0, stream>>>(xcat, Wc, brel2, x2);
  segmax_k<<<782, 256, 0, stream>>>(xcat, x2, batch, g);
  head_k<<<1, 256, 0, stream>>>((const float*)g, exinfo, W1, b1, W2, b2, W3, b3,
                                (float*)d_out);
}

// Round 2
// 444.821 us; speedup vs baseline: 1.4982x; 1.4982x over previous
//
#include <hip/hip_runtime.h>

#define N_NODES 100000
#define N_EDGES 1600000
#define NG 64
#define NC 8
#define HD 128

#define BUCKET_SHIFT 8
#define NB ((N_NODES + 255) >> 8)   /* 391 buckets of 256 nodes */
#define NCHUNK 256
#define EPC (N_EDGES / NCHUNK)      /* 6250 edges per chunk */

typedef __attribute__((ext_vector_type(8))) __bf16 bf16x8;
typedef __attribute__((ext_vector_type(4))) float f32x4;

// ---------------- CSR build via two-level counting sort ----------------
// Pass A: per-chunk LDS histogram over dst-buckets (coalesced writes).

__global__ void bin_hist_k(const int* __restrict__ dst, int* __restrict__ hist) {
  __shared__ int lh[NB];
  int c = blockIdx.x, t = threadIdx.x;
  for (int b = t; b < NB; b += 256) lh[b] = 0;
  __syncthreads();
  int e0 = c * EPC;
  for (int i = t; i < EPC; i += 256) atomicAdd(&lh[dst[e0 + i] >> BUCKET_SHIFT], 1);
  __syncthreads();
  for (int b = t; b < NB; b += 256) hist[c * NB + b] = lh[b];
}

// Bucket totals + exclusive scan -> bucket_base (single block).

__launch_bounds__(512)
__global__ void base_k(const int* __restrict__ hist, int* __restrict__ bucket_base,
                       int* __restrict__ row_ptr) {
  __shared__ int tot[512];
  int t = threadIdx.x;
  int s = 0;
  if (t < NB)
    for (int c = 0; c < NCHUNK; c++) s += hist[c * NB + t];
  tot[t] = s;
  __syncthreads();
  for (int off = 1; off < 512; off <<= 1) {  // Hillis-Steele inclusive scan
    int v = (t >= off) ? tot[t - off] : 0;
    __syncthreads();
    tot[t] += v;
    __syncthreads();
  }
  if (t < NB) bucket_base[t] = tot[t] - s;  // exclusive
  if (t == 0) { bucket_base[NB] = N_EDGES; row_ptr[N_NODES] = N_EDGES; }
}

// Per-bucket scan over chunks: hist[c][b] -> global scatter offset.

__global__ void chunk_scan_k(int* __restrict__ hist, const int* __restrict__ bucket_base) {
  int b = blockIdx.x, lane = threadIdx.x;
  int carry = bucket_base[b];
#pragma unroll
  for (int it = 0; it < NCHUNK / 64; it++) {
    int c = it * 64 + lane;
    int v = hist[c * NB + b];
    int s = v;
#pragma unroll
    for (int off = 1; off < 64; off <<= 1) {
      int u = __shfl_up(s, off);
      if (lane >= off) s += u;
    }
    hist[c * NB + b] = carry + s - v;
    carry += __shfl(s, 63);
  }
}

// Pass B: scatter (dst,src) pairs into per-(chunk,bucket) contiguous cells.

__global__ void scatter_k(const int* __restrict__ src, const int* __restrict__ dst,
                          const int* __restrict__ hist, int2* __restrict__ pairs) {
  __shared__ int loff[NB];
  int c = blockIdx.x, t = threadIdx.x;
  for (int b = t; b < NB; b += 256) loff[b] = hist[c * NB + b];
  __syncthreads();
  int e0 = c * EPC;
  for (int i = t; i < EPC; i += 256) {
    int d = dst[e0 + i], s = src[e0 + i];
    int pos = atomicAdd(&loff[d >> BUCKET_SHIFT], 1);
    pairs[pos] = make_int2(d, s);
  }
}

// Pass C: one WG per bucket -> exact row_ptr + dense csr fill (L2-local writes).

__global__ void bucket_csr_k(const int2* __restrict__ pairs,
                             const int* __restrict__ bucket_base,
                             int* __restrict__ row_ptr, int* __restrict__ csr) {
  __shared__ int cnt[256];
  __shared__ int start[256];
  __shared__ int wsum[4];
  int b = blockIdx.x, t = threadIdx.x, lane = t & 63, wid = t >> 6;
  int nb0 = b << BUCKET_SHIFT;
  int beg = bucket_base[b], end = bucket_base[b + 1];
  cnt[t] = 0;
  __syncthreads();
  for (int i = beg + t; i < end; i += 256) atomicAdd(&cnt[pairs[i].x - nb0], 1);
  __syncthreads();
  int v = cnt[t];
  int s = v;
#pragma unroll
  for (int off = 1; off < 64; off <<= 1) {
    int u = __shfl_up(s, off);
    if (lane >= off) s += u;
  }
  if (lane == 63) wsum[wid] = s;
  __syncthreads();
  if (t == 0) {
    int a = 0;
    for (int j = 0; j < 4; j++) { int x = wsum[j]; wsum[j] = a; a += x; }
  }
  __syncthreads();
  int excl = wsum[wid] + s - v;
  start[t] = excl;
  if (nb0 + t < N_NODES) row_ptr[nb0 + t] = beg + excl;
  cnt[t] = 0;
  __syncthreads();
  for (int i = beg + t; i < end; i += 256) {
    int2 p = pairs[i];
    int li = p.x - nb0;
    int pos = beg + start[li] + atomicAdd(&cnt[li], 1);
    csr[pos] = p.y;
  }
}

// ---------------- conv1: x1 = relu(agg3 @ Wrel1^T + brel1 + xs @ Wroot1^T) ----------------

__global__ void conv1_k(const float* __restrict__ x, const int* __restrict__ row_ptr,
                        const int* __restrict__ csr, const float* __restrict__ Wroot1,
                        const float* __restrict__ Wrel1, const float* __restrict__ brel1,
                        __bf16* __restrict__ xcat) {
  int node = blockIdx.x * 4 + (threadIdx.x >> 6);
  if (node >= N_NODES) return;
  int lane = threadIdx.x & 63;
  int beg = row_ptr[node], end = row_ptr[node + 1];
  int deg = end - beg;
  int idx = (lane < deg) ? csr[beg + lane] : 0;
  float a0 = 0.f, a1 = 0.f, a2 = 0.f;
  int dmain = deg < 64 ? deg : 64;
  for (int j = 0; j < dmain; j++) {
    int s = __shfl(idx, j);
    const float* xp = x + (size_t)s * 5;
    a0 += xp[2]; a1 += xp[3]; a2 += xp[4];
  }
  for (int e = beg + 64; e < end; e++) {
    int s = csr[e];
    const float* xp = x + (size_t)s * 5;
    a0 += xp[2]; a1 += xp[3]; a2 += xp[4];
  }
  const float* xn = x + (size_t)node * 5;
  float r0 = xn[2], r1 = xn[3], r2 = xn[4];
  __bf16* orow = xcat + (size_t)node * 256 + 128;
#pragma unroll
  for (int hh = 0; hh < 2; hh++) {
    int h = lane + hh * 64;
    float v = brel1[h]
            + a0 * Wrel1[h * 3 + 0] + a1 * Wrel1[h * 3 + 1] + a2 * Wrel1[h * 3 + 2]
            + r0 * Wroot1[h * 3 + 0] + r1 * Wroot1[h * 3 + 1] + r2 * Wroot1[h * 3 + 2];
    orow[h] = (__bf16)fmaxf(v, 0.f);
  }
}

// ---------------- agg2: xcat[n][0..127] = sum over in-edges of x1[src] ----------------

__global__ void agg2_k(const int* __restrict__ row_ptr, const int* __restrict__ csr,
                       __bf16* xcat) {
  int node = blockIdx.x * 4 + (threadIdx.x >> 6);
  if (node >= N_NODES) return;
  int lane = threadIdx.x & 63;
  int beg = row_ptr[node], end = row_ptr[node + 1];
  int deg = end - beg;
  int idx = (lane < deg) ? csr[beg + lane] : 0;
  float s0 = 0.f, s1 = 0.f;
  int dmain = deg < 64 ? deg : 64;
  for (int j = 0; j < dmain; j++) {
    int srcn = __shfl(idx, j);
    unsigned int u = ((const unsigned int*)(xcat + (size_t)srcn * 256 + 128))[lane];
    s0 += __uint_as_float(u << 16);
    s1 += __uint_as_float(u & 0xffff0000u);
  }
  for (int e = beg + 64; e < end; e++) {
    int srcn = csr[e];
    unsigned int u = ((const unsigned int*)(xcat + (size_t)srcn * 256 + 128))[lane];
    s0 += __uint_as_float(u << 16);
    s1 += __uint_as_float(u & 0xffff0000u);
  }
  unsigned int lo = __float_as_uint((float)(__bf16)s0) >> 16;
  unsigned int hi = __float_as_uint((float)(__bf16)s1) & 0xffff0000u;
  ((unsigned int*)(xcat + (size_t)node * 256))[lane] = lo | hi;
}

// ---------------- weight concat for conv2 GEMM ----------------

__global__ void build_wc_k(const float* __restrict__ Wrel2, const float* __restrict__ Wroot2,
                           __bf16* __restrict__ Wc) {
  int i = blockIdx.x * 256 + threadIdx.x;
  int h = i >> 8, k = i & 255;
  float v = (k < 128) ? Wrel2[h * 128 + k] : Wroot2[h * 128 + (k - 128)];
  Wc[i] = (__bf16)v;
}

// ---------------- conv2 GEMM: x2 = relu(xcat @ Wc^T + brel2), MFMA bf16 ----------------

__launch_bounds__(256)
__global__ void gemm2_k(const __bf16* __restrict__ xcat, const __bf16* __restrict__ Wc,
                        const float* __restrict__ brel2, __bf16* __restrict__ x2) {
  int wid = threadIdx.x >> 6, lane = threadIdx.x & 63;
  int nb = (blockIdx.x * 4 + wid) * 16;
  if (nb >= N_NODES) return;
  int r = lane & 15, ko = lane >> 4;
  const __bf16* arow = xcat + (size_t)(nb + r) * 256 + ko * 8;
  const __bf16* brow = Wc + (size_t)r * 256 + ko * 8;
  f32x4 acc[8];
#pragma unroll
  for (int i = 0; i < 8; i++) acc[i] = (f32x4){0.f, 0.f, 0.f, 0.f};
#pragma unroll
  for (int kb = 0; kb < 256; kb += 32) {
    bf16x8 a = *(const bf16x8*)(arow + kb);
#pragma unroll
    for (int ht = 0; ht < 8; ht++) {
      bf16x8 b = *(const bf16x8*)(brow + (size_t)ht * 16 * 256 + kb);
      acc[ht] = __builtin_amdgcn_mfma_f32_16x16x32_bf16(a, b, acc[ht], 0, 0, 0);
    }
  }
#pragma unroll
  for (int ht = 0; ht < 8; ht++) {
    int h = ht * 16 + r;
    float bias = brel2[h];
#pragma unroll
    for (int rr = 0; rr < 4; rr++) {
      int node = nb + ko * 4 + rr;
      float v = acc[ht][rr] + bias;
      x2[(size_t)node * 128 + h] = (__bf16)fmaxf(v, 0.f);
    }
  }
}

// ---------------- segment_max over h = [x1 | x2] into g (G x 256) ----------------

__global__ void segmax_k(const __bf16* __restrict__ xcat, const __bf16* __restrict__ x2,
                         const int* __restrict__ batch, unsigned int* __restrict__ g) {
  int t = threadIdx.x;
  int n0 = blockIdx.x * 128;
  if (n0 >= N_NODES) return;
  int n1 = n0 + 128 < N_NODES ? n0 + 128 : N_NODES;
  int cur = batch[n0];
  float m = 0.f;
  for (int n = n0; n < n1; n++) {
    int b = batch[n];
    if (b != cur) {
      atomicMax(&g[cur * 256 + t], __float_as_uint(m));
      cur = b; m = 0.f;
    }
    float v = (t < 128) ? (float)xcat[(size_t)n * 256 + 128 + t]
                        : (float)x2[(size_t)n * 128 + (t - 128)];
    m = fmaxf(m, v);
  }
  atomicMax(&g[cur * 256 + t], __float_as_uint(m));
}

// ---------------- MLP head + log_softmax (single block) ----------------

__global__ void head_k(const float* __restrict__ g, const float* __restrict__ exinfo,
                       const float* __restrict__ W1, const float* __restrict__ b1,
                       const float* __restrict__ W2, const float* __restrict__ b2,
                       const float* __restrict__ W3, const float* __restrict__ b3,
                       float* __restrict__ out) {
  __shared__ float g1[64][64];
  __shared__ float g2[64][32];
  __shared__ float lg[64][8];
  int t = threadIdx.x;
  for (int o = t; o < 64 * 64; o += 256) {
    int rr = o >> 6, c = o & 63;
    float s = b1[c];
    const float* w = W1 + c * 266;
    const float* gr = g + rr * 256;
    for (int k = 0; k < 256; k++) s += gr[k] * w[k];
    const float* er = exinfo + rr * 10;
    for (int k = 0; k < 10; k++) s += er[k] * w[256 + k];
    g1[rr][c] = fmaxf(s, 0.f);
  }
  __syncthreads();
  for (int o = t; o < 64 * 32; o += 256) {
    int rr = o >> 5, c = o & 31;
    float s = b2[c];
    for (int k = 0; k < 64; k++) s += g1[rr][k] * W2[c * 64 + k];
    g2[rr][c] = fmaxf(s, 0.f);
  }
  __syncthreads();
  for (int o = t; o < 64 * 8; o += 256) {
    int rr = o >> 3, c = o & 7;
    float s = b3[c];
    for (int k = 0; k < 32; k++) s += g2[rr][k] * W3[c * 32 + k];
    lg[rr][c] = s;
  }
  __syncthreads();
  if (t < 64) {
    float mx = lg[t][0];
    for (int c = 1; c < 8; c++) mx = fmaxf(mx, lg[t][c]);
    float se = 0.f;
    for (int c = 0; c < 8; c++) se += expf(lg[t][c] - mx);
    float lse = mx + logf(se);
    for (int c = 0; c < 8; c++) out[t * 8 + c] = lg[t][c] - lse;
  }
}

// ---------------- launch ----------------

extern "C" void kernel_launch(void* const* d_in, const int* in_sizes, int n_in,
                              void* d_out, int out_size, void* d_ws, size_t ws_size,
                              hipStream_t stream) {
  const float* x      = (const float*)d_in[0];
  const int*   edge   = (const int*)d_in[1];
  const int*   batch  = (const int*)d_in[2];
  const float* exinfo = (const float*)d_in[3];
  const float* Wroot1 = (const float*)d_in[4];
  const float* Wrel1  = (const float*)d_in[5];
  const float* brel1  = (const float*)d_in[6];
  const float* Wroot2 = (const float*)d_in[7];
  const float* Wrel2  = (const float*)d_in[8];
  const float* brel2  = (const float*)d_in[9];
  const float* W1     = (const float*)d_in[10];
  const float* b1     = (const float*)d_in[11];
  const float* W2     = (const float*)d_in[12];
  const float* b2     = (const float*)d_in[13];
  const float* W3     = (const float*)d_in[14];
  const float* b3     = (const float*)d_in[15];
  const int* src = edge;
  const int* dst = edge + N_EDGES;

  char* p = (char*)d_ws;
  auto alloc = [&](size_t bytes) {
    char* q = p;
    p += (bytes + 511) & ~(size_t)511;
    return (void*)q;
  };
  __bf16*       Wc          = (__bf16*)alloc(128 * 256 * 2);
  unsigned int* g           = (unsigned int*)alloc(64 * 256 * 4);
  int*          hist        = (int*)alloc((size_t)NCHUNK * NB * 4);
  int*          bucket_base = (int*)alloc((size_t)(NB + 1) * 4);
  int*          row_ptr     = (int*)alloc((size_t)(N_NODES + 1) * 4);
  int*          csr         = (int*)alloc((size_t)N_EDGES * 4);
  __bf16*       xcat        = (__bf16*)alloc((size_t)N_NODES * 256 * 2);
  // pairs (12.8 MB) and x2 (25.6 MB) have disjoint lifetimes -> alias.
  void*         xp2         = alloc((size_t)N_NODES * 128 * 2);
  int2*         pairs       = (int2*)xp2;
  __bf16*       x2          = (__bf16*)xp2;

  hipMemsetAsync(g, 0, 64 * 256 * 4, stream);
  build_wc_k<<<128, 256, 0, stream>>>(Wrel2, Wroot2, Wc);
  bin_hist_k<<<NCHUNK, 256, 0, stream>>>(dst, hist);
  base_k<<<1, 512, 0, stream>>>(hist, bucket_base, row_ptr);
  chunk_scan_k<<<NB, 64, 0, stream>>>(hist, bucket_base);
  scatter_k<<<NCHUNK, 256, 0, stream>>>(src, dst, hist, pairs);
  bucket_csr_k<<<NB, 256, 0, stream>>>(pairs, bucket_base, row_ptr, csr);
  conv1_k<<<25000, 256, 0, stream>>>(x, row_ptr, csr, Wroot1, Wrel1, brel1, xcat);
  agg2_k<<<25000, 256, 0, stream>>>(row_ptr, csr, xcat);
  gemm2_k<<<1563, 256, 0, stream>>>(xcat, Wc, brel2, x2);
  segmax_k<<<782, 256, 0, stream>>>(xcat, x2, batch, g);
  head_k<<<1, 256, 0, stream>>>((const float*)g, exinfo, W1, b1, W2, b2, W3, b3,
                                (float*)d_out);
}

// Round 3
// 263.402 us; speedup vs baseline: 2.5301x; 1.6888x over previous
//
#include <hip/hip_runtime.h>

#define N_NODES 100000
#define N_EDGES 1600000
#define NG 64
#define NC 8
#define HD 128

#define BUCKET_SHIFT 8
#define NB ((N_NODES + 255) >> 8)   /* 391 buckets of 256 nodes */
#define NCHUNK 256
#define EPC (N_EDGES / NCHUNK)      /* 6250 edges per chunk */

typedef __attribute__((ext_vector_type(8))) __bf16 bf16x8;
typedef __attribute__((ext_vector_type(4))) float f32x4;

// ---------------- CSR build via two-level counting sort ----------------

__global__ void bin_hist_k(const int* __restrict__ dst, int* __restrict__ hist) {
  __shared__ int lh[NB];
  int c = blockIdx.x, t = threadIdx.x;
  for (int b = t; b < NB; b += 256) lh[b] = 0;
  __syncthreads();
  int e0 = c * EPC;
  for (int i = t; i < EPC; i += 256) atomicAdd(&lh[dst[e0 + i] >> BUCKET_SHIFT], 1);
  __syncthreads();
  for (int b = t; b < NB; b += 256) hist[c * NB + b] = lh[b];
}

__launch_bounds__(512)
__global__ void base_k(const int* __restrict__ hist, int* __restrict__ bucket_base,
                       int* __restrict__ row_ptr) {
  __shared__ int tot[512];
  int t = threadIdx.x;
  int s = 0;
  if (t < NB)
    for (int c = 0; c < NCHUNK; c++) s += hist[c * NB + t];
  tot[t] = s;
  __syncthreads();
  for (int off = 1; off < 512; off <<= 1) {
    int v = (t >= off) ? tot[t - off] : 0;
    __syncthreads();
    tot[t] += v;
    __syncthreads();
  }
  if (t < NB) bucket_base[t] = tot[t] - s;
  if (t == 0) { bucket_base[NB] = N_EDGES; row_ptr[N_NODES] = N_EDGES; }
}

__global__ void chunk_scan_k(int* __restrict__ hist, const int* __restrict__ bucket_base) {
  int b = blockIdx.x, lane = threadIdx.x;
  int carry = bucket_base[b];
#pragma unroll
  for (int it = 0; it < NCHUNK / 64; it++) {
    int c = it * 64 + lane;
    int v = hist[c * NB + b];
    int s = v;
#pragma unroll
    for (int off = 1; off < 64; off <<= 1) {
      int u = __shfl_up(s, off);
      if (lane >= off) s += u;
    }
    hist[c * NB + b] = carry + s - v;
    carry += __shfl(s, 63);
  }
}

__global__ void scatter_k(const int* __restrict__ src, const int* __restrict__ dst,
                          const int* __restrict__ hist, int2* __restrict__ pairs) {
  __shared__ int loff[NB];
  int c = blockIdx.x, t = threadIdx.x;
  for (int b = t; b < NB; b += 256) loff[b] = hist[c * NB + b];
  __syncthreads();
  int e0 = c * EPC;
  for (int i = t; i < EPC; i += 256) {
    int d = dst[e0 + i], s = src[e0 + i];
    int pos = atomicAdd(&loff[d >> BUCKET_SHIFT], 1);
    pairs[pos] = make_int2(d, s);
  }
}

__global__ void bucket_csr_k(const int2* __restrict__ pairs,
                             const int* __restrict__ bucket_base,
                             int* __restrict__ row_ptr, int* __restrict__ csr) {
  __shared__ int cnt[256];
  __shared__ int start[256];
  __shared__ int wsum[4];
  int b = blockIdx.x, t = threadIdx.x, lane = t & 63, wid = t >> 6;
  int nb0 = b << BUCKET_SHIFT;
  int beg = bucket_base[b], end = bucket_base[b + 1];
  cnt[t] = 0;
  __syncthreads();
  for (int i = beg + t; i < end; i += 256) atomicAdd(&cnt[pairs[i].x - nb0], 1);
  __syncthreads();
  int v = cnt[t];
  int s = v;
#pragma unroll
  for (int off = 1; off < 64; off <<= 1) {
    int u = __shfl_up(s, off);
    if (lane >= off) s += u;
  }
  if (lane == 63) wsum[wid] = s;
  __syncthreads();
  if (t == 0) {
    int a = 0;
    for (int j = 0; j < 4; j++) { int x = wsum[j]; wsum[j] = a; a += x; }
  }
  __syncthreads();
  int excl = wsum[wid] + s - v;
  start[t] = excl;
  if (nb0 + t < N_NODES) row_ptr[nb0 + t] = beg + excl;
  cnt[t] = 0;
  __syncthreads();
  for (int i = beg + t; i < end; i += 256) {
    int2 p = pairs[i];
    int li = p.x - nb0;
    int pos = beg + start[li] + atomicAdd(&cnt[li], 1);
    csr[pos] = p.y;
  }
}

// ---------------- conv1: lane-parallel gather + butterfly reduce ----------------

__global__ void conv1_k(const float* __restrict__ x, const int* __restrict__ row_ptr,
                        const int* __restrict__ csr, const float* __restrict__ Wroot1,
                        const float* __restrict__ Wrel1, const float* __restrict__ brel1,
                        __bf16* __restrict__ xcat) {
  int node = blockIdx.x * 4 + (threadIdx.x >> 6);
  if (node >= N_NODES) return;
  int lane = threadIdx.x & 63;
  int beg = row_ptr[node], end = row_ptr[node + 1];
  float a0 = 0.f, a1 = 0.f, a2 = 0.f;
  for (int e = beg + lane; e < end; e += 64) {   // lanes gather edges in parallel
    int s = csr[e];
    const float* xp = x + (size_t)s * 5;
    a0 += xp[2]; a1 += xp[3]; a2 += xp[4];
  }
#pragma unroll
  for (int m = 1; m < 64; m <<= 1) {             // butterfly: all lanes get the sum
    a0 += __shfl_xor(a0, m);
    a1 += __shfl_xor(a1, m);
    a2 += __shfl_xor(a2, m);
  }
  const float* xn = x + (size_t)node * 5;
  float r0 = xn[2], r1 = xn[3], r2 = xn[4];
  __bf16* orow = xcat + (size_t)node * 256 + 128;
#pragma unroll
  for (int hh = 0; hh < 2; hh++) {
    int h = lane + hh * 64;
    float v = brel1[h]
            + a0 * Wrel1[h * 3 + 0] + a1 * Wrel1[h * 3 + 1] + a2 * Wrel1[h * 3 + 2]
            + r0 * Wroot1[h * 3 + 0] + r1 * Wroot1[h * 3 + 1] + r2 * Wroot1[h * 3 + 2];
    orow[h] = (__bf16)fmaxf(v, 0.f);
  }
}

// ---------------- agg2: 4 edges in flight (16 lanes x 16B each), unroll x2 ----------------

__global__ void agg2_k(const int* __restrict__ row_ptr, const int* __restrict__ csr,
                       __bf16* xcat) {
  int node = blockIdx.x * 4 + (threadIdx.x >> 6);
  if (node >= N_NODES) return;
  int lane = threadIdx.x & 63;
  int g = lane >> 4, f = lane & 15;   // g: edge slot, f: 16B feature chunk
  int beg = row_ptr[node], end = row_ptr[node + 1];
  int deg = end - beg;
  int idx = (lane < deg) ? csr[beg + lane] : 0;
  float acc[8];
#pragma unroll
  for (int k = 0; k < 8; k++) acc[k] = 0.f;
  int dmain = deg < 64 ? deg : 64;
  int j = 0;
  for (; j + 8 <= dmain; j += 8) {   // two independent quad-gathers per iter
    int s0 = __shfl(idx, j + g);
    int s1 = __shfl(idx, j + 4 + g);
    uint4 u0 = *((const uint4*)(xcat + (size_t)s0 * 256 + 128) + f);
    uint4 u1 = *((const uint4*)(xcat + (size_t)s1 * 256 + 128) + f);
    acc[0] += __uint_as_float(u0.x << 16);  acc[1] += __uint_as_float(u0.x & 0xffff0000u);
    acc[2] += __uint_as_float(u0.y << 16);  acc[3] += __uint_as_float(u0.y & 0xffff0000u);
    acc[4] += __uint_as_float(u0.z << 16);  acc[5] += __uint_as_float(u0.z & 0xffff0000u);
    acc[6] += __uint_as_float(u0.w << 16);  acc[7] += __uint_as_float(u0.w & 0xffff0000u);
    acc[0] += __uint_as_float(u1.x << 16);  acc[1] += __uint_as_float(u1.x & 0xffff0000u);
    acc[2] += __uint_as_float(u1.y << 16);  acc[3] += __uint_as_float(u1.y & 0xffff0000u);
    acc[4] += __uint_as_float(u1.z << 16);  acc[5] += __uint_as_float(u1.z & 0xffff0000u);
    acc[6] += __uint_as_float(u1.w << 16);  acc[7] += __uint_as_float(u1.w & 0xffff0000u);
  }
  for (; j + 4 <= dmain; j += 4) {
    int s0 = __shfl(idx, j + g);
    uint4 u0 = *((const uint4*)(xcat + (size_t)s0 * 256 + 128) + f);
    acc[0] += __uint_as_float(u0.x << 16);  acc[1] += __uint_as_float(u0.x & 0xffff0000u);
    acc[2] += __uint_as_float(u0.y << 16);  acc[3] += __uint_as_float(u0.y & 0xffff0000u);
    acc[4] += __uint_as_float(u0.z << 16);  acc[5] += __uint_as_float(u0.z & 0xffff0000u);
    acc[6] += __uint_as_float(u0.w << 16);  acc[7] += __uint_as_float(u0.w & 0xffff0000u);
  }
  {
    int rem = dmain - j;                 // 0..3 leftover edges
    int s0 = __shfl(idx, j + (g < rem ? g : 0));
    if (g < rem) {
      uint4 u0 = *((const uint4*)(xcat + (size_t)s0 * 256 + 128) + f);
      acc[0] += __uint_as_float(u0.x << 16);  acc[1] += __uint_as_float(u0.x & 0xffff0000u);
      acc[2] += __uint_as_float(u0.y << 16);  acc[3] += __uint_as_float(u0.y & 0xffff0000u);
      acc[4] += __uint_as_float(u0.z << 16);  acc[5] += __uint_as_float(u0.z & 0xffff0000u);
      acc[6] += __uint_as_float(u0.w << 16);  acc[7] += __uint_as_float(u0.w & 0xffff0000u);
    }
  }
  for (int e = beg + 64; e < end; e += 4) {   // rare deg>64 tail
    int m = end - e;
    int s0 = csr[e + (g < m ? g : 0)];
    if (g < m) {
      uint4 u0 = *((const uint4*)(xcat + (size_t)s0 * 256 + 128) + f);
      acc[0] += __uint_as_float(u0.x << 16);  acc[1] += __uint_as_float(u0.x & 0xffff0000u);
      acc[2] += __uint_as_float(u0.y << 16);  acc[3] += __uint_as_float(u0.y & 0xffff0000u);
      acc[4] += __uint_as_float(u0.z << 16);  acc[5] += __uint_as_float(u0.z & 0xffff0000u);
      acc[6] += __uint_as_float(u0.w << 16);  acc[7] += __uint_as_float(u0.w & 0xffff0000u);
    }
  }
#pragma unroll
  for (int k = 0; k < 8; k++) {   // reduce across the 4 edge-groups
    acc[k] += __shfl_xor(acc[k], 16);
    acc[k] += __shfl_xor(acc[k], 32);
  }
  if (g == 0) {
    uint4 o;
    o.x = (__float_as_uint((float)(__bf16)acc[0]) >> 16) | (__float_as_uint((float)(__bf16)acc[1]) & 0xffff0000u);
    o.y = (__float_as_uint((float)(__bf16)acc[2]) >> 16) | (__float_as_uint((float)(__bf16)acc[3]) & 0xffff0000u);
    o.z = (__float_as_uint((float)(__bf16)acc[4]) >> 16) | (__float_as_uint((float)(__bf16)acc[5]) & 0xffff0000u);
    o.w = (__float_as_uint((float)(__bf16)acc[6]) >> 16) | (__float_as_uint((float)(__bf16)acc[7]) & 0xffff0000u);
    *((uint4*)(xcat + (size_t)node * 256) + f) = o;
  }
}

// ---------------- weight concat for conv2 GEMM ----------------

__global__ void build_wc_k(const float* __restrict__ Wrel2, const float* __restrict__ Wroot2,
                           __bf16* __restrict__ Wc) {
  int i = blockIdx.x * 256 + threadIdx.x;
  int h = i >> 8, k = i & 255;
  float v = (k < 128) ? Wrel2[h * 128 + k] : Wroot2[h * 128 + (k - 128)];
  Wc[i] = (__bf16)v;
}

// ---------------- conv2 GEMM: x2 = relu(xcat @ Wc^T + brel2), MFMA bf16 ----------------

__launch_bounds__(256)
__global__ void gemm2_k(const __bf16* __restrict__ xcat, const __bf16* __restrict__ Wc,
                        const float* __restrict__ brel2, __bf16* __restrict__ x2) {
  int wid = threadIdx.x >> 6, lane = threadIdx.x & 63;
  int nb = (blockIdx.x * 4 + wid) * 16;
  if (nb >= N_NODES) return;
  int r = lane & 15, ko = lane >> 4;
  const __bf16* arow = xcat + (size_t)(nb + r) * 256 + ko * 8;
  const __bf16* brow = Wc + (size_t)r * 256 + ko * 8;
  f32x4 acc[8];
#pragma unroll
  for (int i = 0; i < 8; i++) acc[i] = (f32x4){0.f, 0.f, 0.f, 0.f};
#pragma unroll
  for (int kb = 0; kb < 256; kb += 32) {
    bf16x8 a = *(const bf16x8*)(arow + kb);
#pragma unroll
    for (int ht = 0; ht < 8; ht++) {
      bf16x8 b = *(const bf16x8*)(brow + (size_t)ht * 16 * 256 + kb);
      acc[ht] = __builtin_amdgcn_mfma_f32_16x16x32_bf16(a, b, acc[ht], 0, 0, 0);
    }
  }
#pragma unroll
  for (int ht = 0; ht < 8; ht++) {
    int h = ht * 16 + r;
    float bias = brel2[h];
#pragma unroll
    for (int rr = 0; rr < 4; rr++) {
      int node = nb + ko * 4 + rr;
      float v = acc[ht][rr] + bias;
      x2[(size_t)node * 128 + h] = (__bf16)fmaxf(v, 0.f);
    }
  }
}

// ---------------- segment_max over h = [x1 | x2] into g (G x 256) ----------------

__global__ void segmax_k(const __bf16* __restrict__ xcat, const __bf16* __restrict__ x2,
                         const int* __restrict__ batch, unsigned int* __restrict__ g) {
  int t = threadIdx.x;
  int n0 = blockIdx.x * 128;
  if (n0 >= N_NODES) return;
  int n1 = n0 + 128 < N_NODES ? n0 + 128 : N_NODES;
  int cur = batch[n0];
  float m = 0.f;
  for (int n = n0; n < n1; n++) {
    int b = batch[n];
    if (b != cur) {
      atomicMax(&g[cur * 256 + t], __float_as_uint(m));
      cur = b; m = 0.f;
    }
    float v = (t < 128) ? (float)xcat[(size_t)n * 256 + 128 + t]
                        : (float)x2[(size_t)n * 128 + (t - 128)];
    m = fmaxf(m, v);
  }
  atomicMax(&g[cur * 256 + t], __float_as_uint(m));
}

// ---------------- MLP head: layer1 parallel over 64 groups ----------------

__global__ void head1_k(const float* __restrict__ g, const float* __restrict__ exinfo,
                        const float* __restrict__ W1, const float* __restrict__ b1,
                        float* __restrict__ g1) {
  int gg = blockIdx.x;         // 64 blocks, one per group
  int t = threadIdx.x;         // 256 = 64 outputs x 4 lanes
  int c = t >> 2, q = t & 3;
  const float* w = W1 + c * 266;
  const float* gr = g + gg * 256;
  float s = 0.f;
  for (int k = q * 64; k < q * 64 + 64; k++) s += gr[k] * w[k];
  if (q == 0) {
    const float* er = exinfo + gg * 10;
    for (int k = 0; k < 10; k++) s += er[k] * w[256 + k];
    s += b1[c];
  }
  s += __shfl_xor(s, 1);
  s += __shfl_xor(s, 2);
  if (q == 0) g1[gg * 64 + c] = fmaxf(s, 0.f);
}

__global__ void head2_k(const float* __restrict__ g1, const float* __restrict__ W2,
                        const float* __restrict__ b2, const float* __restrict__ W3,
                        const float* __restrict__ b3, float* __restrict__ out) {
  __shared__ float s1[64 * 64];
  __shared__ float s2[64 * 32];
  int t = threadIdx.x;
  for (int i = t; i < 4096; i += 256) s1[i] = g1[i];
  __syncthreads();
  for (int o = t; o < 2048; o += 256) {
    int r = o >> 5, c = o & 31;
    float s = b2[c];
    for (int k = 0; k < 64; k++) s += s1[r * 64 + k] * W2[c * 64 + k];
    s2[r * 32 + c] = fmaxf(s, 0.f);
  }
  __syncthreads();
  if (t < 64) {
    float lg[8];
#pragma unroll
    for (int c = 0; c < 8; c++) {
      float s = b3[c];
      for (int k = 0; k < 32; k++) s += s2[t * 32 + k] * W3[c * 32 + k];
      lg[c] = s;
    }
    float mx = lg[0];
#pragma unroll
    for (int c = 1; c < 8; c++) mx = fmaxf(mx, lg[c]);
    float se = 0.f;
#pragma unroll
    for (int c = 0; c < 8; c++) se += expf(lg[c] - mx);
    float lse = mx + logf(se);
#pragma unroll
    for (int c = 0; c < 8; c++) out[t * 8 + c] = lg[c] - lse;
  }
}

// ---------------- launch ----------------

extern "C" void kernel_launch(void* const* d_in, const int* in_sizes, int n_in,
                              void* d_out, int out_size, void* d_ws, size_t ws_size,
                              hipStream_t stream) {
  const float* x      = (const float*)d_in[0];
  const int*   edge   = (const int*)d_in[1];
  const int*   batch  = (const int*)d_in[2];
  const float* exinfo = (const float*)d_in[3];
  const float* Wroot1 = (const float*)d_in[4];
  const float* Wrel1  = (const float*)d_in[5];
  const float* brel1  = (const float*)d_in[6];
  const float* Wroot2 = (const float*)d_in[7];
  const float* Wrel2  = (const float*)d_in[8];
  const float* brel2  = (const float*)d_in[9];
  const float* W1     = (const float*)d_in[10];
  const float* b1     = (const float*)d_in[11];
  const float* W2     = (const float*)d_in[12];
  const float* b2     = (const float*)d_in[13];
  const float* W3     = (const float*)d_in[14];
  const float* b3     = (const float*)d_in[15];
  const int* src = edge;
  const int* dst = edge + N_EDGES;

  char* p = (char*)d_ws;
  auto alloc = [&](size_t bytes) {
    char* q = p;
    p += (bytes + 511) & ~(size_t)511;
    return (void*)q;
  };
  __bf16*       Wc          = (__bf16*)alloc(128 * 256 * 2);
  unsigned int* g           = (unsigned int*)alloc(64 * 256 * 4);
  float*        g1          = (float*)alloc(64 * 64 * 4);
  int*          hist        = (int*)alloc((size_t)NCHUNK * NB * 4);
  int*          bucket_base = (int*)alloc((size_t)(NB + 1) * 4);
  int*          row_ptr     = (int*)alloc((size_t)(N_NODES + 1) * 4);
  int*          csr         = (int*)alloc((size_t)N_EDGES * 4);
  __bf16*       xcat        = (__bf16*)alloc((size_t)N_NODES * 256 * 2);
  void*         xp2         = alloc((size_t)N_NODES * 128 * 2);
  int2*         pairs       = (int2*)xp2;   // aliases x2 (disjoint lifetime)
  __bf16*       x2          = (__bf16*)xp2;

  hipMemsetAsync(g, 0, 64 * 256 * 4, stream);
  build_wc_k<<<128, 256, 0, stream>>>(Wrel2, Wroot2, Wc);
  bin_hist_k<<<NCHUNK, 256, 0, stream>>>(dst, hist);
  base_k<<<1, 512, 0, stream>>>(hist, bucket_base, row_ptr);
  chunk_scan_k<<<NB, 64, 0, stream>>>(hist, bucket_base);
  scatter_k<<<NCHUNK, 256, 0, stream>>>(src, dst, hist, pairs);
  bucket_csr_k<<<NB, 256, 0, stream>>>(pairs, bucket_base, row_ptr, csr);
  conv1_k<<<25000, 256, 0, stream>>>(x, row_ptr, csr, Wroot1, Wrel1, brel1, xcat);
  agg2_k<<<25000, 256, 0, stream>>>(row_ptr, csr, xcat);
  gemm2_k<<<1563, 256, 0, stream>>>(xcat, Wc, brel2, x2);
  segmax_k<<<782, 256, 0, stream>>>(xcat, x2, batch, g);
  head1_k<<<64, 256, 0, stream>>>((const float*)g, exinfo, W1, b1, g1);
  head2_k<<<1, 256, 0, stream>>>(g1, W2, b2, W3, b3, (float*)d_out);
}

// Round 5
// 246.389 us; speedup vs baseline: 2.7048x; 1.0690x over previous
//
#include <hip/hip_runtime.h>

#define N_NODES 100000
#define N_EDGES 1600000
#define NG 64
#define NC 8
#define HD 128

#define BUCKET_SHIFT 8
#define NB ((N_NODES + 255) >> 8)   /* 391 buckets of 256 nodes */
#define NCHUNK 256
#define EPC (N_EDGES / NCHUNK)      /* 6250 edges per chunk */

typedef __attribute__((ext_vector_type(8))) __bf16 bf16x8;
typedef __attribute__((ext_vector_type(4))) float f32x4;

// ---------------- CSR build via two-level counting sort ----------------

__global__ void bin_hist_k(const int* __restrict__ dst, int* __restrict__ hist) {
  __shared__ int lh[NB];
  int c = blockIdx.x, t = threadIdx.x;
  for (int b = t; b < NB; b += 256) lh[b] = 0;
  __syncthreads();
  int e0 = c * EPC;
  for (int i = t; i < EPC; i += 256) atomicAdd(&lh[dst[e0 + i] >> BUCKET_SHIFT], 1);
  __syncthreads();
  for (int b = t; b < NB; b += 256) hist[c * NB + b] = lh[b];
}

__launch_bounds__(512)
__global__ void base_k(const int* __restrict__ hist, int* __restrict__ bucket_base,
                       int* __restrict__ row_ptr) {
  __shared__ int tot[512];
  int t = threadIdx.x;
  int s = 0;
  if (t < NB)
    for (int c = 0; c < NCHUNK; c++) s += hist[c * NB + t];
  tot[t] = s;
  __syncthreads();
  for (int off = 1; off < 512; off <<= 1) {
    int v = (t >= off) ? tot[t - off] : 0;
    __syncthreads();
    tot[t] += v;
    __syncthreads();
  }
  if (t < NB) bucket_base[t] = tot[t] - s;
  if (t == 0) { bucket_base[NB] = N_EDGES; row_ptr[N_NODES] = N_EDGES; }
}

__global__ void chunk_scan_k(int* __restrict__ hist, const int* __restrict__ bucket_base) {
  int b = blockIdx.x, lane = threadIdx.x;
  int carry = bucket_base[b];
#pragma unroll
  for (int it = 0; it < NCHUNK / 64; it++) {
    int c = it * 64 + lane;
    int v = hist[c * NB + b];
    int s = v;
#pragma unroll
    for (int off = 1; off < 64; off <<= 1) {
      int u = __shfl_up(s, off);
      if (lane >= off) s += u;
    }
    hist[c * NB + b] = carry + s - v;
    carry += __shfl(s, 63);
  }
}

__global__ void scatter_k(const int* __restrict__ src, const int* __restrict__ dst,
                          const int* __restrict__ hist, int2* __restrict__ pairs) {
  __shared__ int loff[NB];
  int c = blockIdx.x, t = threadIdx.x;
  for (int b = t; b < NB; b += 256) loff[b] = hist[c * NB + b];
  __syncthreads();
  int e0 = c * EPC;
  for (int i = t; i < EPC; i += 256) {
    int d = dst[e0 + i], s = src[e0 + i];
    int pos = atomicAdd(&loff[d >> BUCKET_SHIFT], 1);
    pairs[pos] = make_int2(d, s);
  }
}

__global__ void bucket_csr_k(const int2* __restrict__ pairs,
                             const int* __restrict__ bucket_base,
                             int* __restrict__ row_ptr, int* __restrict__ csr) {
  __shared__ int cnt[256];
  __shared__ int start[256];
  __shared__ int wsum[4];
  int b = blockIdx.x, t = threadIdx.x, lane = t & 63, wid = t >> 6;
  int nb0 = b << BUCKET_SHIFT;
  int beg = bucket_base[b], end = bucket_base[b + 1];
  cnt[t] = 0;
  __syncthreads();
  for (int i = beg + t; i < end; i += 256) atomicAdd(&cnt[pairs[i].x - nb0], 1);
  __syncthreads();
  int v = cnt[t];
  int s = v;
#pragma unroll
  for (int off = 1; off < 64; off <<= 1) {
    int u = __shfl_up(s, off);
    if (lane >= off) s += u;
  }
  if (lane == 63) wsum[wid] = s;
  __syncthreads();
  if (t == 0) {
    int a = 0;
    for (int j = 0; j < 4; j++) { int x = wsum[j]; wsum[j] = a; a += x; }
  }
  __syncthreads();
  int excl = wsum[wid] + s - v;
  start[t] = excl;
  if (nb0 + t < N_NODES) row_ptr[nb0 + t] = beg + excl;
  cnt[t] = 0;
  __syncthreads();
  for (int i = beg + t; i < end; i += 256) {
    int2 p = pairs[i];
    int li = p.x - nb0;
    int pos = beg + start[li] + atomicAdd(&cnt[li], 1);
    csr[pos] = p.y;
  }
}

// ---------------- conv1: lane-parallel gather + butterfly reduce ----------------

__global__ void conv1_k(const float* __restrict__ x, const int* __restrict__ row_ptr,
                        const int* __restrict__ csr, const float* __restrict__ Wroot1,
                        const float* __restrict__ Wrel1, const float* __restrict__ brel1,
                        __bf16* __restrict__ xcat) {
  int node = blockIdx.x * 4 + (threadIdx.x >> 6);
  if (node >= N_NODES) return;
  int lane = threadIdx.x & 63;
  int beg = row_ptr[node], end = row_ptr[node + 1];
  float a0 = 0.f, a1 = 0.f, a2 = 0.f;
  for (int e = beg + lane; e < end; e += 64) {
    int s = csr[e];
    const float* xp = x + (size_t)s * 5;
    a0 += xp[2]; a1 += xp[3]; a2 += xp[4];
  }
#pragma unroll
  for (int m = 1; m < 64; m <<= 1) {
    a0 += __shfl_xor(a0, m);
    a1 += __shfl_xor(a1, m);
    a2 += __shfl_xor(a2, m);
  }
  const float* xn = x + (size_t)node * 5;
  float r0 = xn[2], r1 = xn[3], r2 = xn[4];
  __bf16* orow = xcat + (size_t)node * 256 + 128;
#pragma unroll
  for (int hh = 0; hh < 2; hh++) {
    int h = lane + hh * 64;
    float v = brel1[h]
            + a0 * Wrel1[h * 3 + 0] + a1 * Wrel1[h * 3 + 1] + a2 * Wrel1[h * 3 + 2]
            + r0 * Wroot1[h * 3 + 0] + r1 * Wroot1[h * 3 + 1] + r2 * Wroot1[h * 3 + 2];
    orow[h] = (__bf16)fmaxf(v, 0.f);
  }
}

// ---------------- agg2: 4 edges in flight (16 lanes x 16B each), unroll x2 ----------------

__global__ void agg2_k(const int* __restrict__ row_ptr, const int* __restrict__ csr,
                       __bf16* xcat) {
  int node = blockIdx.x * 4 + (threadIdx.x >> 6);
  if (node >= N_NODES) return;
  int lane = threadIdx.x & 63;
  int g = lane >> 4, f = lane & 15;
  int beg = row_ptr[node], end = row_ptr[node + 1];
  int deg = end - beg;
  int idx = (lane < deg) ? csr[beg + lane] : 0;
  float acc[8];
#pragma unroll
  for (int k = 0; k < 8; k++) acc[k] = 0.f;
  int dmain = deg < 64 ? deg : 64;
  int j = 0;
  for (; j + 8 <= dmain; j += 8) {
    int s0 = __shfl(idx, j + g);
    int s1 = __shfl(idx, j + 4 + g);
    uint4 u0 = *((const uint4*)(xcat + (size_t)s0 * 256 + 128) + f);
    uint4 u1 = *((const uint4*)(xcat + (size_t)s1 * 256 + 128) + f);
    acc[0] += __uint_as_float(u0.x << 16);  acc[1] += __uint_as_float(u0.x & 0xffff0000u);
    acc[2] += __uint_as_float(u0.y << 16);  acc[3] += __uint_as_float(u0.y & 0xffff0000u);
    acc[4] += __uint_as_float(u0.z << 16);  acc[5] += __uint_as_float(u0.z & 0xffff0000u);
    acc[6] += __uint_as_float(u0.w << 16);  acc[7] += __uint_as_float(u0.w & 0xffff0000u);
    acc[0] += __uint_as_float(u1.x << 16);  acc[1] += __uint_as_float(u1.x & 0xffff0000u);
    acc[2] += __uint_as_float(u1.y << 16);  acc[3] += __uint_as_float(u1.y & 0xffff0000u);
    acc[4] += __uint_as_float(u1.z << 16);  acc[5] += __uint_as_float(u1.z & 0xffff0000u);
    acc[6] += __uint_as_float(u1.w << 16);  acc[7] += __uint_as_float(u1.w & 0xffff0000u);
  }
  for (; j + 4 <= dmain; j += 4) {
    int s0 = __shfl(idx, j + g);
    uint4 u0 = *((const uint4*)(xcat + (size_t)s0 * 256 + 128) + f);
    acc[0] += __uint_as_float(u0.x << 16);  acc[1] += __uint_as_float(u0.x & 0xffff0000u);
    acc[2] += __uint_as_float(u0.y << 16);  acc[3] += __uint_as_float(u0.y & 0xffff0000u);
    acc[4] += __uint_as_float(u0.z << 16);  acc[5] += __uint_as_float(u0.z & 0xffff0000u);
    acc[6] += __uint_as_float(u0.w << 16);  acc[7] += __uint_as_float(u0.w & 0xffff0000u);
  }
  {
    int rem = dmain - j;
    int s0 = __shfl(idx, j + (g < rem ? g : 0));
    if (g < rem) {
      uint4 u0 = *((const uint4*)(xcat + (size_t)s0 * 256 + 128) + f);
      acc[0] += __uint_as_float(u0.x << 16);  acc[1] += __uint_as_float(u0.x & 0xffff0000u);
      acc[2] += __uint_as_float(u0.y << 16);  acc[3] += __uint_as_float(u0.y & 0xffff0000u);
      acc[4] += __uint_as_float(u0.z << 16);  acc[5] += __uint_as_float(u0.z & 0xffff0000u);
      acc[6] += __uint_as_float(u0.w << 16);  acc[7] += __uint_as_float(u0.w & 0xffff0000u);
    }
  }
  for (int e = beg + 64; e < end; e += 4) {
    int m = end - e;
    int s0 = csr[e + (g < m ? g : 0)];
    if (g < m) {
      uint4 u0 = *((const uint4*)(xcat + (size_t)s0 * 256 + 128) + f);
      acc[0] += __uint_as_float(u0.x << 16);  acc[1] += __uint_as_float(u0.x & 0xffff0000u);
      acc[2] += __uint_as_float(u0.y << 16);  acc[3] += __uint_as_float(u0.y & 0xffff0000u);
      acc[4] += __uint_as_float(u0.z << 16);  acc[5] += __uint_as_float(u0.z & 0xffff0000u);
      acc[6] += __uint_as_float(u0.w << 16);  acc[7] += __uint_as_float(u0.w & 0xffff0000u);
    }
  }
#pragma unroll
  for (int k = 0; k < 8; k++) {
    acc[k] += __shfl_xor(acc[k], 16);
    acc[k] += __shfl_xor(acc[k], 32);
  }
  if (g == 0) {
    uint4 o;
    o.x = (__float_as_uint((float)(__bf16)acc[0]) >> 16) | (__float_as_uint((float)(__bf16)acc[1]) & 0xffff0000u);
    o.y = (__float_as_uint((float)(__bf16)acc[2]) >> 16) | (__float_as_uint((float)(__bf16)acc[3]) & 0xffff0000u);
    o.z = (__float_as_uint((float)(__bf16)acc[4]) >> 16) | (__float_as_uint((float)(__bf16)acc[5]) & 0xffff0000u);
    o.w = (__float_as_uint((float)(__bf16)acc[6]) >> 16) | (__float_as_uint((float)(__bf16)acc[7]) & 0xffff0000u);
    *((uint4*)(xcat + (size_t)node * 256) + f) = o;
  }
}

// ---------------- weight concat for conv2 GEMM ----------------

__global__ void build_wc_k(const float* __restrict__ Wrel2, const float* __restrict__ Wroot2,
                           __bf16* __restrict__ Wc) {
  int i = blockIdx.x * 256 + threadIdx.x;
  int h = i >> 8, k = i & 255;
  float v = (k < 128) ? Wrel2[h * 128 + k] : Wroot2[h * 128 + (k - 128)];
  Wc[i] = (__bf16)v;
}

// ---------------- conv2 GEMM: 32 nodes/wave, B-frags reused across 2 M-tiles ----------------

__launch_bounds__(256)
__global__ void gemm2_k(const __bf16* __restrict__ xcat, const __bf16* __restrict__ Wc,
                        const float* __restrict__ brel2, __bf16* __restrict__ x2) {
  int wid = threadIdx.x >> 6, lane = threadIdx.x & 63;
  int nb = (blockIdx.x * 4 + wid) * 32;
  if (nb >= N_NODES) return;
  int r = lane & 15, ko = lane >> 4;
  const __bf16* arow0 = xcat + (size_t)(nb + r) * 256 + ko * 8;
  const __bf16* arow1 = arow0 + 16 * 256;
  const __bf16* brow = Wc + (size_t)r * 256 + ko * 8;
  f32x4 acc0[8], acc1[8];
#pragma unroll
  for (int i = 0; i < 8; i++) {
    acc0[i] = (f32x4){0.f, 0.f, 0.f, 0.f};
    acc1[i] = (f32x4){0.f, 0.f, 0.f, 0.f};
  }
#pragma unroll
  for (int kb = 0; kb < 256; kb += 32) {
    bf16x8 a0 = *(const bf16x8*)(arow0 + kb);
    bf16x8 a1 = *(const bf16x8*)(arow1 + kb);
#pragma unroll
    for (int ht = 0; ht < 8; ht++) {
      bf16x8 b = *(const bf16x8*)(brow + (size_t)ht * 16 * 256 + kb);
      acc0[ht] = __builtin_amdgcn_mfma_f32_16x16x32_bf16(a0, b, acc0[ht], 0, 0, 0);
      acc1[ht] = __builtin_amdgcn_mfma_f32_16x16x32_bf16(a1, b, acc1[ht], 0, 0, 0);
    }
  }
#pragma unroll
  for (int ht = 0; ht < 8; ht++) {
    int h = ht * 16 + r;
    float bias = brel2[h];
#pragma unroll
    for (int rr = 0; rr < 4; rr++) {
      int node = nb + ko * 4 + rr;
      x2[(size_t)node * 128 + h] = (__bf16)fmaxf(acc0[ht][rr] + bias, 0.f);
      x2[(size_t)(node + 16) * 128 + h] = (__bf16)fmaxf(acc1[ht][rr] + bias, 0.f);
    }
  }
}

// ---------------- segment_max over h = [x1 | x2] into g (G x 256) ----------------

__global__ void segmax_k(const __bf16* __restrict__ xcat, const __bf16* __restrict__ x2,
                         const int* __restrict__ batch, unsigned int* __restrict__ g) {
  int t = threadIdx.x;
  int n0 = blockIdx.x * 128;
  if (n0 >= N_NODES) return;
  int n1 = n0 + 128 < N_NODES ? n0 + 128 : N_NODES;
  int cur = batch[n0];
  float m = 0.f;
  for (int n = n0; n < n1; n++) {
    int b = batch[n];
    if (b != cur) {
      atomicMax(&g[cur * 256 + t], __float_as_uint(m));
      cur = b; m = 0.f;
    }
    float v = (t < 128) ? (float)xcat[(size_t)n * 256 + 128 + t]
                        : (float)x2[(size_t)n * 128 + (t - 128)];
    m = fmaxf(m, v);
  }
  atomicMax(&g[cur * 256 + t], __float_as_uint(m));
}

// ---------------- MLP head ----------------

__global__ void head1_k(const float* __restrict__ g, const float* __restrict__ exinfo,
                        const float* __restrict__ W1, const float* __restrict__ b1,
                        float* __restrict__ g1) {
  int gg = blockIdx.x;
  int t = threadIdx.x;
  int c = t >> 2, q = t & 3;
  const float* w = W1 + c * 266;
  const float* gr = g + gg * 256;
  float s = 0.f;
  for (int k = q * 64; k < q * 64 + 64; k++) s += gr[k] * w[k];
  if (q == 0) {
    const float* er = exinfo + gg * 10;
    for (int k = 0; k < 10; k++) s += er[k] * w[256 + k];
    s += b1[c];
  }
  s += __shfl_xor(s, 1);
  s += __shfl_xor(s, 2);
  if (q == 0) g1[gg * 64 + c] = fmaxf(s, 0.f);
}

__global__ void head2_k(const float* __restrict__ g1, const float* __restrict__ W2,
                        const float* __restrict__ b2, const float* __restrict__ W3,
                        const float* __restrict__ b3, float* __restrict__ out) {
  __shared__ float s1[64 * 64];
  __shared__ float s2[64 * 32];
  int t = threadIdx.x;
  for (int i = t; i < 4096; i += 256) s1[i] = g1[i];
  __syncthreads();
  for (int o = t; o < 2048; o += 256) {
    int r = o >> 5, c = o & 31;
    float s = b2[c];
    for (int k = 0; k < 64; k++) s += s1[r * 64 + k] * W2[c * 64 + k];
    s2[r * 32 + c] = fmaxf(s, 0.f);
  }
  __syncthreads();
  if (t < 64) {
    float lg[8];
#pragma unroll
    for (int c = 0; c < 8; c++) {
      float s = b3[c];
      for (int k = 0; k < 32; k++) s += s2[t * 32 + k] * W3[c * 32 + k];
      lg[c] = s;
    }
    float mx = lg[0];
#pragma unroll
    for (int c = 1; c < 8; c++) mx = fmaxf(mx, lg[c]);
    float se = 0.f;
#pragma unroll
    for (int c = 0; c < 8; c++) se += expf(lg[c] - mx);
    float lse = mx + logf(se);
#pragma unroll
    for (int c = 0; c < 8; c++) out[t * 8 + c] = lg[c] - lse;
  }
}

// ---------------- launch ----------------

extern "C" void kernel_launch(void* const* d_in, const int* in_sizes, int n_in,
                              void* d_out, int out_size, void* d_ws, size_t ws_size,
                              hipStream_t stream) {
  const float* x      = (const float*)d_in[0];
  const int*   edge   = (const int*)d_in[1];
  const int*   batch  = (const int*)d_in[2];
  const float* exinfo = (const float*)d_in[3];
  const float* Wroot1 = (const float*)d_in[4];
  const float* Wrel1  = (const float*)d_in[5];
  const float* brel1  = (const float*)d_in[6];
  const float* Wroot2 = (const float*)d_in[7];
  const float* Wrel2  = (const float*)d_in[8];
  const float* brel2  = (const float*)d_in[9];
  const float* W1     = (const float*)d_in[10];
  const float* b1     = (const float*)d_in[11];
  const float* W2     = (const float*)d_in[12];
  const float* b2     = (const float*)d_in[13];
  const float* W3     = (const float*)d_in[14];
  const float* b3     = (const float*)d_in[15];
  const int* src = edge;
  const int* dst = edge + N_EDGES;

  char* p = (char*)d_ws;
  auto alloc = [&](size_t bytes) {
    char* q = p;
    p += (bytes + 511) & ~(size_t)511;
    return (void*)q;
  };
  __bf16*       Wc          = (__bf16*)alloc(128 * 256 * 2);
  unsigned int* g           = (unsigned int*)alloc(64 * 256 * 4);
  float*        g1          = (float*)alloc(64 * 64 * 4);
  int*          hist        = (int*)alloc((size_t)NCHUNK * NB * 4);
  int*          bucket_base = (int*)alloc((size_t)(NB + 1) * 4);
  int*          row_ptr     = (int*)alloc((size_t)(N_NODES + 1) * 4);
  int*          csr         = (int*)alloc((size_t)N_EDGES * 4);
  __bf16*       xcat        = (__bf16*)alloc((size_t)N_NODES * 256 * 2);
  void*         xp2         = alloc((size_t)N_NODES * 128 * 2);
  int2*         pairs       = (int2*)xp2;   // aliases x2 (disjoint lifetime)
  __bf16*       x2          = (__bf16*)xp2;

  hipMemsetAsync(g, 0, 64 * 256 * 4, stream);
  build_wc_k<<<128, 256, 0, stream>>>(Wrel2, Wroot2, Wc);
  bin_hist_k<<<NCHUNK, 256, 0, stream>>>(dst, hist);
  base_k<<<1, 512, 0, stream>>>(hist, bucket_base, row_ptr);
  chunk_scan_k<<<NB, 64, 0, stream>>>(hist, bucket_base);
  scatter_k<<<NCHUNK, 256, 0, stream>>>(src, dst, hist, pairs);
  bucket_csr_k<<<NB, 256, 0, stream>>>(pairs, bucket_base, row_ptr, csr);
  conv1_k<<<25000, 256, 0, stream>>>(x, row_ptr, csr, Wroot1, Wrel1, brel1, xcat);
  agg2_k<<<25000, 256, 0, stream>>>(row_ptr, csr, xcat);
  gemm2_k<<<782, 256, 0, stream>>>(xcat, Wc, brel2, x2);
  segmax_k<<<782, 256, 0, stream>>>(xcat, x2, batch, g);
  head1_k<<<64, 256, 0, stream>>>((const float*)g, exinfo, W1, b1, g1);
  head2_k<<<1, 256, 0, stream>>>(g1, W2, b2, W3, b3, (float*)d_out);
}